// Round 4
// baseline (362.684 us; speedup 1.0000x reference)
//
#include <hip/hip_runtime.h>

constexpr int cB = 32;
constexpr int cS = 1024;
constexpr int cD = 1280;
constexpr int KC = 16;          // k-chunk for split-K qk matmul
constexpr int NKC = cD / KC;    // 80 k-chunks
constexpr int NNC = cD / 256;   // 5 n-chunks
constexpr int RB = 8;           // attn rows per block
constexpr int NSC = cS / RB;    // 128 row-chunks per batch
constexpr int NPART = cB * NSC; // 4096 softmax partials

#define LN_EPS 1e-5f
#define MASK_FILL -1e9f
#define SCALE 0.02795084971874737f   // 1280^-0.5

// ============================================================================
// Row-dot matmul vs W^T:  out[b*cD+n] = bias[n] + dot(A[b,:], W[n,:])
// Grid 640 x 256 (2560 waves). Wave owns one W row (read once into regs),
// loops 16 batches with independent loads -> deep ILP, no atomics.
// ============================================================================
__global__ __launch_bounds__(256) void k_dotT(const float* __restrict__ A,
                                              size_t lda,
                                              const float* __restrict__ W,
                                              const float* __restrict__ bias,
                                              float* __restrict__ out) {
    int w = threadIdx.x >> 6, lane = threadIdx.x & 63;
    int gw = blockIdx.x * 4 + w;            // 0..2559
    int n = gw >> 1;                        // W row
    int bh = (gw & 1) * 16;                 // batch half
    int d0 = lane * 4;

    float4 wr[5];
#pragma unroll
    for (int it = 0; it < 5; ++it)
        wr[it] = *reinterpret_cast<const float4*>(W + (size_t)n * cD + it * 256 + d0);
    float bn = bias[n];

#pragma unroll
    for (int bi = 0; bi < 16; ++bi) {
        int b = bh + bi;
        const float* a = A + (size_t)b * lda + d0;
        float4 av[5];
#pragma unroll
        for (int it = 0; it < 5; ++it)
            av[it] = *reinterpret_cast<const float4*>(a + it * 256);
        float dot = 0.f;
#pragma unroll
        for (int it = 0; it < 5; ++it)
            dot += av[it].x * wr[it].x + av[it].y * wr[it].y
                 + av[it].z * wr[it].z + av[it].w * wr[it].w;
#pragma unroll
        for (int off = 32; off; off >>= 1) dot += __shfl_xor(dot, off, 64);
        if (lane == 0) out[b * cD + n] = dot + bn;
    }
}

// ============================================================================
// Split-K phase 1 (no atomics), B row-major [K,N]:
//   part[kc][b][n] = sum_{k in chunk} A[b,k] * B[k,n]
// Grid 400 = 5 nc x 80 kc. A loads wave-uniform -> s_load.
// ============================================================================
__global__ __launch_bounds__(256) void k_mm_p1(const float* __restrict__ A,
                                               const float* __restrict__ B,
                                               float* __restrict__ part) {
    int t = threadIdx.x;
    int nc = blockIdx.x % NNC, kc = blockIdx.x / NNC;
    int n0 = nc * 256, k0 = kc * KC;

    float w[KC];
#pragma unroll
    for (int kk = 0; kk < KC; ++kk)
        w[kk] = B[(size_t)(k0 + kk) * cD + n0 + t];   // coalesced

#pragma unroll
    for (int b = 0; b < cB; ++b) {
        const float* Ab = A + (size_t)b * cD + k0;    // wave-uniform -> s_load
        float a0 = 0.f, a1 = 0.f, a2 = 0.f, a3 = 0.f;
#pragma unroll
        for (int kk = 0; kk < KC; kk += 4) {
            a0 += Ab[kk + 0] * w[kk + 0];
            a1 += Ab[kk + 1] * w[kk + 1];
            a2 += Ab[kk + 2] * w[kk + 2];
            a3 += Ab[kk + 3] * w[kk + 3];
        }
        part[(size_t)kc * (cB * cD) + b * cD + n0 + t] = (a0 + a1) + (a2 + a3);
    }
}

// ---------------- phase 2: qk = sum partials ; last block: qb = q0.bk --------
__global__ __launch_bounds__(256) void k_mm_red_qb(const float* __restrict__ part,
                                                   const float* __restrict__ q0,
                                                   const float* __restrict__ bk,
                                                   float* __restrict__ qk,
                                                   float* __restrict__ qb) {
    if (blockIdx.x < 160) {
        int i = blockIdx.x * 256 + threadIdx.x;       // 0..cB*cD-1
        float s = 0.f;
#pragma unroll
        for (int c = 0; c < NKC; ++c) s += part[(size_t)c * (cB * cD) + i];
        qk[i] = s;
    } else {
        int w = threadIdx.x >> 6, lane = threadIdx.x & 63;
        int d0 = lane * 4;
        float4 bkr[5];
#pragma unroll
        for (int it = 0; it < 5; ++it)
            bkr[it] = *reinterpret_cast<const float4*>(bk + it * 256 + d0);
#pragma unroll
        for (int r = 0; r < 8; ++r) {
            int b = w * 8 + r;
            float dot = 0.f;
#pragma unroll
            for (int it = 0; it < 5; ++it) {
                float4 qv = *reinterpret_cast<const float4*>(q0 + b * cD + it * 256 + d0);
                dot += qv.x * bkr[it].x + qv.y * bkr[it].y
                     + qv.z * bkr[it].z + qv.w * bkr[it].w;
            }
#pragma unroll
            for (int off = 32; off; off >>= 1) dot += __shfl_xor(dot, off, 64);
            if (lane == 0) qb[b] = dot;
        }
    }
}

// ============================================================================
// v4 k_attn: stage-then-compute. Block = 8 rows (40 KB LDS tile).
//   phase 1: pure streaming stage of the 8-row tile into LDS (address-math
//            only -> full HBM BW; 3 blocks/CU interleave stage & compute)
//   phase 2: dots from LDS (per-lane column slices IDENTICAL to verified
//            kernel -> bit-identical dot values), wave w does rows 2w,2w+1
//   phase 3: batch softmax over the 8 block-local scores (no online rescale
//            needed), per-thread redundant
//   phase 4: weighted sum: thread owns 5 columns, reduces over 8 rows from
//            LDS -> pacc row complete, no cross-wave combine needed.
// Grid 32*128 = 4096; pm/pl/pacc have 4096 partials (combined by k_attn_red).
// ============================================================================
__global__ __launch_bounds__(256) void k_attn(const float* __restrict__ emb,
                                              const float* __restrict__ qk,
                                              const float* __restrict__ qb,
                                              const int* __restrict__ mask,
                                              float* __restrict__ pm,
                                              float* __restrict__ pl,
                                              float* __restrict__ pacc) {
    __shared__ float tile[RB * cD];      // 40960 B
    __shared__ float s_sc[RB];
    int blk = blockIdx.x;
    int b = blk >> 7, sc = blk & (NSC - 1);
    int tid = threadIdx.x, w = tid >> 6, lane = tid & 63;
    int d0 = lane * 4;
    int s0 = sc * RB;

    // qk fragment for the dot phase (same per-lane slices as verified kernel)
    float4 qkr[5];
#pragma unroll
    for (int it = 0; it < 5; ++it)
        qkr[it] = *reinterpret_cast<const float4*>(qk + b * cD + it * 256 + d0);
    float qbv = qb[b];

    // ---- phase 1: stage 8 rows (2560 float4, 10 per thread, coalesced) ----
    const float4* src = reinterpret_cast<const float4*>(
        emb + ((size_t)b * cS + s0) * cD);
    float4* dst = reinterpret_cast<float4*>(tile);
#pragma unroll
    for (int i = 0; i < 10; ++i)
        dst[i * 256 + tid] = src[i * 256 + tid];
    __syncthreads();

    // ---- phase 2: dots from LDS; wave w -> rows 2w, 2w+1 ----
#pragma unroll
    for (int rr = 0; rr < 2; ++rr) {
        int r = w * 2 + rr;
        const float* trow = tile + r * cD + d0;
        float dot = 0.f;
#pragma unroll
        for (int it = 0; it < 5; ++it) {
            float4 ev = *reinterpret_cast<const float4*>(trow + it * 256);
            dot += ev.x * qkr[it].x + ev.y * qkr[it].y
                 + ev.z * qkr[it].z + ev.w * qkr[it].w;
        }
#pragma unroll
        for (int off = 32; off; off >>= 1) dot += __shfl_xor(dot, off, 64);
        if (lane == 0) s_sc[r] = dot;
    }
    __syncthreads();

    // ---- phase 3: block-local batch softmax (per-thread redundant) ----
    float scv[RB], m = -INFINITY;
#pragma unroll
    for (int r = 0; r < RB; ++r) {
        scv[r] = (mask[b * cS + s0 + r] == 0) ? MASK_FILL
                                              : (s_sc[r] + qbv) * SCALE;
        m = fmaxf(m, scv[r]);
    }
    float p[RB], l = 0.f;
#pragma unroll
    for (int r = 0; r < RB; ++r) { p[r] = __expf(scv[r] - m); l += p[r]; }

    // ---- phase 4: weighted sum; thread owns cols tid + 256*j ----
#pragma unroll
    for (int j = 0; j < 5; ++j) {
        int col = j * 256 + tid;
        float a = 0.f;
#pragma unroll
        for (int r = 0; r < RB; ++r) a += p[r] * tile[r * cD + col];
        pacc[(size_t)blk * cD + col] = a;
    }
    if (tid == 0) { pm[blk] = m; pl[blk] = l; }
}

// ---------------- combine 128 partials per batch -> ectx ---------------------
__global__ __launch_bounds__(256) void k_attn_red(const float* __restrict__ pm,
                                                  const float* __restrict__ pl,
                                                  const float* __restrict__ pacc,
                                                  float* __restrict__ ectx) {
    int b = blockIdx.x / 5, j = blockIdx.x % 5;
    int d = j * 256 + threadIdx.x;
    float M = -INFINITY;
    for (int i = 0; i < NSC; ++i) M = fmaxf(M, pm[b * NSC + i]);
    float L = 0.f, a = 0.f;
    for (int i = 0; i < NSC; ++i) {
        float wf = __expf(pm[b * NSC + i] - M);
        L += pl[b * NSC + i] * wf;
        a += wf * pacc[(size_t)(b * NSC + i) * cD + d];
    }
    ectx[b * cD + d] = a / L;
}

// ---------------- LayerNorm + ReLU -------------------------------------------
__global__ __launch_bounds__(256) void k_ln(const float* __restrict__ h,
                                            const float* __restrict__ gamma,
                                            const float* __restrict__ beta,
                                            float* __restrict__ out) {
    int b = blockIdx.x;
    __shared__ float red[8];
    int wid = threadIdx.x >> 6, lane = threadIdx.x & 63;
    float v[5];
    float sum = 0.f;
#pragma unroll
    for (int j = 0; j < 5; ++j) {
        v[j] = h[b * cD + threadIdx.x + 256 * j];
        sum += v[j];
    }
#pragma unroll
    for (int off = 32; off; off >>= 1) sum += __shfl_xor(sum, off, 64);
    if (lane == 0) red[wid] = sum;
    __syncthreads();
    float mu = (red[0] + red[1] + red[2] + red[3]) * (1.f / cD);
    float vs = 0.f;
#pragma unroll
    for (int j = 0; j < 5; ++j) { float t = v[j] - mu; vs += t * t; }
#pragma unroll
    for (int off = 32; off; off >>= 1) vs += __shfl_xor(vs, off, 64);
    if (lane == 0) red[4 + wid] = vs;
    __syncthreads();
    float var = (red[4] + red[5] + red[6] + red[7]) * (1.f / cD);
    float inv = rsqrtf(var + LN_EPS);
#pragma unroll
    for (int j = 0; j < 5; ++j) {
        int idx = threadIdx.x + 256 * j;
        float o = (v[j] - mu) * inv * gamma[idx] + beta[idx];
        out[b * cD + idx] = fmaxf(o, 0.f);
    }
}

extern "C" void kernel_launch(void* const* d_in, const int* in_sizes, int n_in,
                              void* d_out, int out_size, void* d_ws, size_t ws_size,
                              hipStream_t stream) {
    const float* emb   = (const float*)d_in[0];
    const int*   mask  = (const int*)d_in[1];
    const float* Wq    = (const float*)d_in[2];
    const float* bq    = (const float*)d_in[3];
    const float* Wk    = (const float*)d_in[4];
    const float* bk    = (const float*)d_in[5];
    const float* Wv    = (const float*)d_in[6];
    const float* bv    = (const float*)d_in[7];
    const float* Wo    = (const float*)d_in[8];
    const float* bo    = (const float*)d_in[9];
    const float* gamma = (const float*)d_in[10];
    const float* beta  = (const float*)d_in[11];

    float* ws   = (float*)d_ws;
    float* part = ws;                        // 80*32*1280 = 3,276,800
    float* q0   = part + NKC * cB * cD;      // 40960
    float* qk   = q0 + cB * cD;              // 40960
    float* qb   = qk + cB * cD;              // 32
    float* pm   = qb + cB;                   // 4096
    float* pl   = pm + NPART;                // 4096
    float* pacc = pl + NPART;                // 4096*1280
    float* ectx = pacc + (size_t)NPART * cD; // 40960
    float* ctx  = ectx + cB * cD;            // 40960
    float* h    = ctx + cB * cD;             // 40960

    // q0 = emb[:,0,:] @ Wq^T + bq       (row-dot, 2560 waves)
    k_dotT<<<640, 256, 0, stream>>>(emb, (size_t)cS * cD, Wq, bq, q0);
    // qk = q0 @ Wk  (split-K, 400 blocks, no atomics)
    k_mm_p1<<<NNC * NKC, 256, 0, stream>>>(q0, Wk, part);
    // qk reduce + qb = q0 . bk
    k_mm_red_qb<<<161, 256, 0, stream>>>(part, q0, bk, qk, qb);
    // fused scores + softmax + weighted emb sum (stage-then-compute)
    k_attn<<<NPART, 256, 0, stream>>>(emb, qk, qb, mask, pm, pl, pacc);
    k_attn_red<<<160, 256, 0, stream>>>(pm, pl, pacc, ectx);
    // ctx = ectx @ Wv^T + bv            (row-dot)
    k_dotT<<<640, 256, 0, stream>>>(ectx, (size_t)cD, Wv, bv, ctx);
    // h = ctx @ Wo^T + bo               (row-dot)
    k_dotT<<<640, 256, 0, stream>>>(ctx, (size_t)cD, Wo, bo, h);
    // LayerNorm + ReLU
    k_ln<<<cB, 256, 0, stream>>>(h, gamma, beta, (float*)d_out);
}

// Round 6
// 346.109 us; speedup vs baseline: 1.0479x; 1.0479x over previous
//
#include <hip/hip_runtime.h>

constexpr int cB = 32;
constexpr int cS = 1024;
constexpr int cD = 1280;
constexpr int NNC = cD / 256;   // 5 n-chunks for k_qk

#define LN_EPS 1e-5f
#define MASK_FILL -1e9f
#define SCALE 0.02795084971874737f   // 1280^-0.5

// ============================================================================
// Row-dot matmul vs W^T:  out[b*cD+n] = bias[n] + dot(A[b,:], W[n,:])
// Grid 640 x 256 (2560 waves). Wave owns one W row (read once into regs),
// loops 16 batches accumulating 16 dots; ALL 16 shuffle-trees run after the
// loop (independent -> 16-wide ILP instead of serial tree on critical path).
// Per-lane adds and per-tree order identical to verified kernel.
// ============================================================================
__global__ __launch_bounds__(256) void k_dotT(const float* __restrict__ A,
                                              size_t lda,
                                              const float* __restrict__ W,
                                              const float* __restrict__ bias,
                                              float* __restrict__ out) {
    int w = threadIdx.x >> 6, lane = threadIdx.x & 63;
    int gw = blockIdx.x * 4 + w;            // 0..2559
    int n = gw >> 1;                        // W row
    int bh = (gw & 1) * 16;                 // batch half
    int d0 = lane * 4;

    float4 wr[5];
#pragma unroll
    for (int it = 0; it < 5; ++it)
        wr[it] = *reinterpret_cast<const float4*>(W + (size_t)n * cD + it * 256 + d0);
    float bn = bias[n];

    float dot[16];
#pragma unroll
    for (int bi = 0; bi < 16; ++bi) {
        int b = bh + bi;
        const float* a = A + (size_t)b * lda + d0;
        float4 av[5];
#pragma unroll
        for (int it = 0; it < 5; ++it)
            av[it] = *reinterpret_cast<const float4*>(a + it * 256);
        float d = 0.f;
#pragma unroll
        for (int it = 0; it < 5; ++it)
            d += av[it].x * wr[it].x + av[it].y * wr[it].y
               + av[it].z * wr[it].z + av[it].w * wr[it].w;
        dot[bi] = d;
    }
    // 16 independent butterfly trees, interleaved per level (hides shfl latency)
#pragma unroll
    for (int off = 32; off; off >>= 1)
#pragma unroll
        for (int bi = 0; bi < 16; ++bi)
            dot[bi] += __shfl_xor(dot[bi], off, 64);
    if (lane == 0) {
#pragma unroll
        for (int bi = 0; bi < 16; ++bi)
            out[(bh + bi) * cD + n] = dot[bi] + bn;
    }
}

// ============================================================================
// k_qk: one-dispatch replacement for split-K + reduce.
//   blocks 0..159: (b = bid/5, nc = bid%5); thread t computes
//     qk[b, nc*256+t] = sum_k q0[b,k] * Wk[k, nc*256+t]
//   (Wk loads coalesced across threads; q0 loads wave-uniform -> s_load;
//    8 independent accumulators for ILP)
//   block 160: qb[b] = q0[b,:] . bk   (verbatim math from verified kernel,
//    with the 8 shuffle-trees batched after the loop)
// ============================================================================
__global__ __launch_bounds__(256) void k_qk(const float* __restrict__ q0,
                                            const float* __restrict__ Wk,
                                            const float* __restrict__ bk,
                                            float* __restrict__ qk,
                                            float* __restrict__ qb) {
    if (blockIdx.x < 160) {
        int b = blockIdx.x / NNC, nc = blockIdx.x % NNC;
        int n = nc * 256 + threadIdx.x;
        const float* Ab = q0 + (size_t)b * cD;        // wave-uniform -> s_load
        const float* Wp = Wk + n;
        float a0 = 0.f, a1 = 0.f, a2 = 0.f, a3 = 0.f;
        float a4 = 0.f, a5 = 0.f, a6 = 0.f, a7 = 0.f;
        for (int kk = 0; kk < cD; kk += 8) {
            const float* wrow = Wp + (size_t)kk * cD;
            a0 += Ab[kk + 0] * wrow[0 * cD];
            a1 += Ab[kk + 1] * wrow[1 * cD];
            a2 += Ab[kk + 2] * wrow[2 * cD];
            a3 += Ab[kk + 3] * wrow[3 * cD];
            a4 += Ab[kk + 4] * wrow[4 * cD];
            a5 += Ab[kk + 5] * wrow[5 * cD];
            a6 += Ab[kk + 6] * wrow[6 * cD];
            a7 += Ab[kk + 7] * wrow[7 * cD];
        }
        qk[(size_t)b * cD + n] =
            ((a0 + a1) + (a2 + a3)) + ((a4 + a5) + (a6 + a7));
    } else {
        int w = threadIdx.x >> 6, lane = threadIdx.x & 63;
        int d0 = lane * 4;
        float4 bkr[5];
#pragma unroll
        for (int it = 0; it < 5; ++it)
            bkr[it] = *reinterpret_cast<const float4*>(bk + it * 256 + d0);
        float dot[8];
#pragma unroll
        for (int r = 0; r < 8; ++r) {
            int b = w * 8 + r;
            float d = 0.f;
#pragma unroll
            for (int it = 0; it < 5; ++it) {
                float4 qv = *reinterpret_cast<const float4*>(q0 + b * cD + it * 256 + d0);
                d += qv.x * bkr[it].x + qv.y * bkr[it].y
                   + qv.z * bkr[it].z + qv.w * bkr[it].w;
            }
            dot[r] = d;
        }
#pragma unroll
        for (int off = 32; off; off >>= 1)
#pragma unroll
            for (int r = 0; r < 8; ++r)
                dot[r] += __shfl_xor(dot[r], off, 64);
        if (lane == 0) {
#pragma unroll
            for (int r = 0; r < 8; ++r) qb[w * 8 + r] = dot[r];
        }
    }
}

// ============================================================================
// Fused flash-style: scores + online softmax + weighted emb sum. VERBATIM
// from round-3 (proven 345.2): 2-deep pipelined, reg-accum online softmax.
// Grid: b*32 + sc ; block 256 = 4 waves ; wave handles 8 consecutive s-rows.
// ============================================================================
__global__ __launch_bounds__(256) void k_attn(const float* __restrict__ emb,
                                              const float* __restrict__ qk,
                                              const float* __restrict__ qb,
                                              const int* __restrict__ mask,
                                              float* __restrict__ pm,
                                              float* __restrict__ pl,
                                              float* __restrict__ pacc) {
    __shared__ float s_all[4][cD];
    __shared__ float s_m[4], s_l[4];
    int blk = blockIdx.x;
    int b = blk >> 5, sc = blk & 31;
    int w = threadIdx.x >> 6, lane = threadIdx.x & 63;
    int d0 = lane * 4;

    float4 qkr[5];
#pragma unroll
    for (int it = 0; it < 5; ++it)
        qkr[it] = *reinterpret_cast<const float4*>(qk + b * cD + it * 256 + d0);
    float qbv = qb[b];

    float m = -INFINITY, l = 0.f;
    float4 acc[5];
#pragma unroll
    for (int it = 0; it < 5; ++it) acc[it] = make_float4(0.f, 0.f, 0.f, 0.f);

    int s0 = sc * 32 + w * 8;
    const float* ebase = emb + (size_t)(b * cS + s0) * cD + d0;

#define ATTN_ROW(rIdx, er)                                                     \
    {                                                                          \
        int s = s0 + (rIdx);                                                   \
        float dot = 0.f;                                                       \
        _Pragma("unroll")                                                      \
        for (int it = 0; it < 5; ++it)                                         \
            dot += er[it].x * qkr[it].x + er[it].y * qkr[it].y                 \
                 + er[it].z * qkr[it].z + er[it].w * qkr[it].w;                \
        _Pragma("unroll")                                                      \
        for (int off = 32; off; off >>= 1) dot += __shfl_xor(dot, off, 64);    \
        float scv = (mask[b * cS + s] == 0) ? MASK_FILL : (dot + qbv) * SCALE; \
        if (scv > m) {                                                         \
            float f = __expf(m - scv);                                         \
            l *= f;                                                            \
            _Pragma("unroll")                                                  \
            for (int it = 0; it < 5; ++it) {                                   \
                acc[it].x *= f; acc[it].y *= f;                                \
                acc[it].z *= f; acc[it].w *= f;                                \
            }                                                                  \
            m = scv;                                                           \
        }                                                                      \
        float p = __expf(scv - m);                                             \
        l += p;                                                                \
        _Pragma("unroll")                                                      \
        for (int it = 0; it < 5; ++it) {                                       \
            acc[it].x += p * er[it].x; acc[it].y += p * er[it].y;              \
            acc[it].z += p * er[it].z; acc[it].w += p * er[it].w;              \
        }                                                                      \
    }

    float4 erA[5], erB[5];
#pragma unroll
    for (int it = 0; it < 5; ++it)
        erA[it] = *reinterpret_cast<const float4*>(ebase + it * 256);

#pragma unroll
    for (int rr = 0; rr < 8; rr += 2) {
#pragma unroll
        for (int it = 0; it < 5; ++it)
            erB[it] = *reinterpret_cast<const float4*>(
                ebase + (size_t)(rr + 1) * cD + it * 256);
        ATTN_ROW(rr, erA);
        if (rr + 2 < 8) {
#pragma unroll
            for (int it = 0; it < 5; ++it)
                erA[it] = *reinterpret_cast<const float4*>(
                    ebase + (size_t)(rr + 2) * cD + it * 256);
        }
        ATTN_ROW(rr + 1, erB);
    }
#undef ATTN_ROW

    // ---- block combine: parallel over 4 waves ----
    if (lane == 0) { s_m[w] = m; s_l[w] = l; }
    __syncthreads();
    float M = fmaxf(fmaxf(s_m[0], s_m[1]), fmaxf(s_m[2], s_m[3]));
    float f = __expf(m - M);                 // wave-uniform
#pragma unroll
    for (int it = 0; it < 5; ++it)
        *reinterpret_cast<float4*>(&s_all[w][it * 256 + d0]) =
            make_float4(acc[it].x * f, acc[it].y * f, acc[it].z * f, acc[it].w * f);
    __syncthreads();

    if (threadIdx.x == 0) {
        float lt = s_l[0] * __expf(s_m[0] - M) + s_l[1] * __expf(s_m[1] - M)
                 + s_l[2] * __expf(s_m[2] - M) + s_l[3] * __expf(s_m[3] - M);
        pm[blk] = M; pl[blk] = lt;
    }
#pragma unroll
    for (int j = 0; j < 5; ++j) {
        int d = j * 256 + threadIdx.x;
        pacc[(size_t)blk * cD + d] =
            s_all[0][d] + s_all[1][d] + s_all[2][d] + s_all[3][d];
    }
}

// ---------------- combine 32 partials per batch -> ectx ----------------------
__global__ __launch_bounds__(256) void k_attn_red(const float* __restrict__ pm,
                                                  const float* __restrict__ pl,
                                                  const float* __restrict__ pacc,
                                                  float* __restrict__ ectx) {
    int b = blockIdx.x / 5, j = blockIdx.x % 5;
    int d = j * 256 + threadIdx.x;
    float M = -INFINITY;
#pragma unroll 8
    for (int i = 0; i < 32; ++i) M = fmaxf(M, pm[b * 32 + i]);
    float L = 0.f, a = 0.f;
#pragma unroll 8
    for (int i = 0; i < 32; ++i) {
        float wf = __expf(pm[b * 32 + i] - M);
        L += pl[b * 32 + i] * wf;
        a += wf * pacc[(size_t)(b * 32 + i) * cD + d];
    }
    ectx[b * cD + d] = a / L;
}

// ---------------- LayerNorm + ReLU -------------------------------------------
__global__ __launch_bounds__(256) void k_ln(const float* __restrict__ h,
                                            const float* __restrict__ gamma,
                                            const float* __restrict__ beta,
                                            float* __restrict__ out) {
    int b = blockIdx.x;
    __shared__ float red[8];
    int wid = threadIdx.x >> 6, lane = threadIdx.x & 63;
    float v[5];
    float sum = 0.f;
#pragma unroll
    for (int j = 0; j < 5; ++j) {
        v[j] = h[b * cD + threadIdx.x + 256 * j];
        sum += v[j];
    }
#pragma unroll
    for (int off = 32; off; off >>= 1) sum += __shfl_xor(sum, off, 64);
    if (lane == 0) red[wid] = sum;
    __syncthreads();
    float mu = (red[0] + red[1] + red[2] + red[3]) * (1.f / cD);
    float vs = 0.f;
#pragma unroll
    for (int j = 0; j < 5; ++j) { float t = v[j] - mu; vs += t * t; }
#pragma unroll
    for (int off = 32; off; off >>= 1) vs += __shfl_xor(vs, off, 64);
    if (lane == 0) red[4 + wid] = vs;
    __syncthreads();
    float var = (red[4] + red[5] + red[6] + red[7]) * (1.f / cD);
    float inv = rsqrtf(var + LN_EPS);
#pragma unroll
    for (int j = 0; j < 5; ++j) {
        int idx = threadIdx.x + 256 * j;
        float o = (v[j] - mu) * inv * gamma[idx] + beta[idx];
        out[b * cD + idx] = fmaxf(o, 0.f);
    }
}

extern "C" void kernel_launch(void* const* d_in, const int* in_sizes, int n_in,
                              void* d_out, int out_size, void* d_ws, size_t ws_size,
                              hipStream_t stream) {
    const float* emb   = (const float*)d_in[0];
    const int*   mask  = (const int*)d_in[1];
    const float* Wq    = (const float*)d_in[2];
    const float* bq    = (const float*)d_in[3];
    const float* Wk    = (const float*)d_in[4];
    const float* bk    = (const float*)d_in[5];
    const float* Wv    = (const float*)d_in[6];
    const float* bv    = (const float*)d_in[7];
    const float* Wo    = (const float*)d_in[8];
    const float* bo    = (const float*)d_in[9];
    const float* gamma = (const float*)d_in[10];
    const float* beta  = (const float*)d_in[11];

    float* ws   = (float*)d_ws;
    float* q0   = ws;                        // 40960
    float* qk   = q0 + cB * cD;              // 40960
    float* qb   = qk + cB * cD;              // 32
    float* pm   = qb + cB;                   // 1024
    float* pl   = pm + 1024;                 // 1024
    float* pacc = pl + 1024;                 // 1024*1280
    float* ectx = pacc + (size_t)1024 * cD;  // 40960
    float* ctx  = ectx + cB * cD;            // 40960
    float* h    = ctx + cB * cD;             // 40960

    // q0 = emb[:,0,:] @ Wq^T + bq       (row-dot, 2560 waves)
    k_dotT<<<640, 256, 0, stream>>>(emb, (size_t)cS * cD, Wq, bq, q0);
    // qk = q0 @ Wk ; qb = q0 . bk       (single dispatch, direct full-K)
    k_qk<<<161, 256, 0, stream>>>(q0, Wk, bk, qk, qb);
    // fused scores + softmax + weighted emb sum (2-deep pipelined)
    k_attn<<<cB * 32, 256, 0, stream>>>(emb, qk, qb, mask, pm, pl, pacc);
    k_attn_red<<<160, 256, 0, stream>>>(pm, pl, pacc, ectx);
    // ctx = ectx @ Wv^T + bv            (row-dot)
    k_dotT<<<640, 256, 0, stream>>>(ectx, (size_t)cD, Wv, bv, ctx);
    // h = ctx @ Wo^T + bo               (row-dot)
    k_dotT<<<640, 256, 0, stream>>>(ctx, (size_t)cD, Wo, bo, h);
    // LayerNorm + ReLU
    k_ln<<<cB, 256, 0, stream>>>(h, gamma, beta, (float*)d_out);
}